// Round 5
// baseline (19783.714 us; speedup 1.0000x reference)
//
#include <hip/hip_runtime.h>

#define HID 64
#define IN_DIM 128
#define TAU_DIM 8
#define SCAN_B 1024

// ---------------- CSR build ----------------
// All index inputs are bounds-guarded: malformed edge data must produce a
// wrong answer (validation failure), never a device memory fault.

__global__ void zero_int_kernel(int* __restrict__ p, int n) {
    int i = blockIdx.x * blockDim.x + threadIdx.x;
    if (i < n) p[i] = 0;
}

__global__ void count_deg_kernel(const int* __restrict__ row, int* __restrict__ deg,
                                 int e, int n) {
    int i = blockIdx.x * blockDim.x + threadIdx.x;
    if (i < e) {
        int r = row[i];
        if ((unsigned)r < (unsigned)n) atomicAdd(&deg[r], 1);
    }
}

__global__ void block_sum_kernel(const int* __restrict__ deg, int* __restrict__ blk, int n) {
    __shared__ int s[SCAN_B];
    int i = blockIdx.x * SCAN_B + threadIdx.x;
    s[threadIdx.x] = (i < n) ? deg[i] : 0;
    __syncthreads();
    for (int off = SCAN_B / 2; off > 0; off >>= 1) {
        if (threadIdx.x < off) s[threadIdx.x] += s[threadIdx.x + off];
        __syncthreads();
    }
    if (threadIdx.x == 0) blk[blockIdx.x] = s[0];
}

__global__ void scan_blk_kernel(int* __restrict__ blk, int nb) {
    __shared__ int s[SCAN_B];
    int v = (threadIdx.x < nb) ? blk[threadIdx.x] : 0;
    s[threadIdx.x] = v;
    __syncthreads();
    for (int off = 1; off < SCAN_B; off <<= 1) {
        int t = (threadIdx.x >= off) ? s[threadIdx.x - off] : 0;
        __syncthreads();
        s[threadIdx.x] += t;
        __syncthreads();
    }
    if (threadIdx.x < nb) blk[threadIdx.x] = s[threadIdx.x] - v;  // exclusive
}

__global__ void scan_final_kernel(const int* __restrict__ deg, const int* __restrict__ blk,
                                  int* __restrict__ row_start, int* __restrict__ cursor, int n) {
    __shared__ int s[SCAN_B];
    int i = blockIdx.x * SCAN_B + threadIdx.x;
    int v = (i < n) ? deg[i] : 0;
    s[threadIdx.x] = v;
    __syncthreads();
    for (int off = 1; off < SCAN_B; off <<= 1) {
        int t = (threadIdx.x >= off) ? s[threadIdx.x - off] : 0;
        __syncthreads();
        s[threadIdx.x] += t;
        __syncthreads();
    }
    if (i < n) {
        int excl = s[threadIdx.x] - v + blk[blockIdx.x];
        row_start[i] = excl;
        cursor[i]    = excl;
    }
}

__global__ void fill_csr_kernel(const int* __restrict__ row, const int* __restrict__ col,
                                int* __restrict__ cursor, int* __restrict__ cols,
                                int e, int n) {
    int i = blockIdx.x * blockDim.x + threadIdx.x;
    if (i < e) {
        int r = row[i];
        if ((unsigned)r < (unsigned)n) {
            int c = col[i];
            if ((unsigned)c >= (unsigned)n) c = 0;  // never store an OOB index
            int p = atomicAdd(&cursor[r], 1);
            cols[p] = c;
        }
    }
}

// ---------------- init: h0 = relu(x@W_in.T+b), tau = mean(sigmoid(relu(x@W_t1.T+b)@W_t2.T+b)) ----------------

__global__ __launch_bounds__(256) void init_kernel(
    const float* __restrict__ x,
    const float* __restrict__ W_in, const float* __restrict__ b_in,
    const float* __restrict__ W_t1, const float* __restrict__ b_t1,
    const float* __restrict__ W_t2, const float* __restrict__ b_t2,
    float* __restrict__ h, float* __restrict__ tau, int n) {
    int v = blockIdx.x * blockDim.x + threadIdx.x;
    if (v >= n) return;

    float4 xr[32];
    const float4* xp = (const float4*)(x + (size_t)v * IN_DIM);
#pragma unroll
    for (int k = 0; k < 32; k++) xr[k] = xp[k];

    float* hv = h + (size_t)v * HID;
#pragma unroll 1
    for (int jg = 0; jg < 16; jg++) {
        int j = jg * 4;
        float a0 = b_in[j], a1 = b_in[j + 1], a2 = b_in[j + 2], a3 = b_in[j + 3];
        const float4* w0 = (const float4*)(W_in + (size_t)(j + 0) * IN_DIM);
        const float4* w1 = (const float4*)(W_in + (size_t)(j + 1) * IN_DIM);
        const float4* w2 = (const float4*)(W_in + (size_t)(j + 2) * IN_DIM);
        const float4* w3 = (const float4*)(W_in + (size_t)(j + 3) * IN_DIM);
#pragma unroll
        for (int k = 0; k < 32; k++) {
            float4 xv = xr[k];
            float4 wa = w0[k], wb = w1[k], wc = w2[k], wd = w3[k];
            a0 += wa.x * xv.x + wa.y * xv.y + wa.z * xv.z + wa.w * xv.w;
            a1 += wb.x * xv.x + wb.y * xv.y + wb.z * xv.z + wb.w * xv.w;
            a2 += wc.x * xv.x + wc.y * xv.y + wc.z * xv.z + wc.w * xv.w;
            a3 += wd.x * xv.x + wd.y * xv.y + wd.z * xv.z + wd.w * xv.w;
        }
        *(float4*)(hv + j) = make_float4(fmaxf(a0, 0.f), fmaxf(a1, 0.f),
                                         fmaxf(a2, 0.f), fmaxf(a3, 0.f));
    }

    float t_acc[TAU_DIM];
#pragma unroll
    for (int m = 0; m < TAU_DIM; m++) t_acc[m] = b_t2[m];

#pragma unroll 1
    for (int jg = 0; jg < 16; jg++) {
        int j = jg * 4;
        float a0 = b_t1[j], a1 = b_t1[j + 1], a2 = b_t1[j + 2], a3 = b_t1[j + 3];
        const float4* w0 = (const float4*)(W_t1 + (size_t)(j + 0) * IN_DIM);
        const float4* w1 = (const float4*)(W_t1 + (size_t)(j + 1) * IN_DIM);
        const float4* w2 = (const float4*)(W_t1 + (size_t)(j + 2) * IN_DIM);
        const float4* w3 = (const float4*)(W_t1 + (size_t)(j + 3) * IN_DIM);
#pragma unroll
        for (int k = 0; k < 32; k++) {
            float4 xv = xr[k];
            float4 wa = w0[k], wb = w1[k], wc = w2[k], wd = w3[k];
            a0 += wa.x * xv.x + wa.y * xv.y + wa.z * xv.z + wa.w * xv.w;
            a1 += wb.x * xv.x + wb.y * xv.y + wb.z * xv.z + wb.w * xv.w;
            a2 += wc.x * xv.x + wc.y * xv.y + wc.z * xv.z + wc.w * xv.w;
            a3 += wd.x * xv.x + wd.y * xv.y + wd.z * xv.z + wd.w * xv.w;
        }
        a0 = fmaxf(a0, 0.f); a1 = fmaxf(a1, 0.f); a2 = fmaxf(a2, 0.f); a3 = fmaxf(a3, 0.f);
#pragma unroll
        for (int m = 0; m < TAU_DIM; m++) {
            t_acc[m] += W_t2[(size_t)m * HID + j]     * a0
                      + W_t2[(size_t)m * HID + j + 1] * a1
                      + W_t2[(size_t)m * HID + j + 2] * a2
                      + W_t2[(size_t)m * HID + j + 3] * a3;
        }
    }
    float tsum = 0.f;
#pragma unroll
    for (int m = 0; m < TAU_DIM; m++) tsum += 1.f / (1.f + expf(-t_acc[m]));
    tau[v] = tsum * (1.f / TAU_DIM);
}

// ---------------- aggregate: agg[v] = tau[v] * sum_e |h[v]-h[col[e]]| ----------------

__global__ __launch_bounds__(256) void aggregate_kernel(
    const float* __restrict__ h, const float* __restrict__ tau,
    const int* __restrict__ row_start, const int* __restrict__ deg,
    const int* __restrict__ cols, float* __restrict__ agg, int n) {
    int t = blockIdx.x * blockDim.x + threadIdx.x;
    int v = t >> 4;
    if (v >= n) return;
    int c4 = (t & 15) * 4;

    float4 hv = *(const float4*)(h + (size_t)v * HID + c4);
    float4 s0 = make_float4(0.f, 0.f, 0.f, 0.f);
    float4 s1 = make_float4(0.f, 0.f, 0.f, 0.f);
    int st = row_start[v];
    int d  = deg[v];
    int i = 0;
    for (; i + 1 < d; i += 2) {
        int c0 = cols[st + i];
        int c1 = cols[st + i + 1];
        float4 hc0 = *(const float4*)(h + (size_t)c0 * HID + c4);
        float4 hc1 = *(const float4*)(h + (size_t)c1 * HID + c4);
        s0.x += fabsf(hv.x - hc0.x);
        s0.y += fabsf(hv.y - hc0.y);
        s0.z += fabsf(hv.z - hc0.z);
        s0.w += fabsf(hv.w - hc0.w);
        s1.x += fabsf(hv.x - hc1.x);
        s1.y += fabsf(hv.y - hc1.y);
        s1.z += fabsf(hv.z - hc1.z);
        s1.w += fabsf(hv.w - hc1.w);
    }
    if (i < d) {
        int c = cols[st + i];
        float4 hc = *(const float4*)(h + (size_t)c * HID + c4);
        s0.x += fabsf(hv.x - hc.x);
        s0.y += fabsf(hv.y - hc.y);
        s0.z += fabsf(hv.z - hc.z);
        s0.w += fabsf(hv.w - hc.w);
    }
    float tv = tau[v];
    *(float4*)(agg + (size_t)v * HID + c4) =
        make_float4((s0.x + s1.x) * tv, (s0.y + s1.y) * tv,
                    (s0.z + s1.z) * tv, (s0.w + s1.w) * tv);
}

// ---------------- GRU cell, quarter-split, ping-pong (race-free) ----------------
// blockIdx.x = (node_tile << 2) | quarter. Each thread = one node, computes
// outputs j in [q*16, q*16+16). Reads h_cur (read-only this launch), writes
// h_nxt — the 4 quarter-blocks of a node never race. Quarter's 96 weight rows
// (24 KB) + biases staged in LDS; dot-product reads are same-address
// broadcasts (conflict-free).

__global__ __launch_bounds__(256) void gru_kernel(
    const float* __restrict__ agg, const float* __restrict__ h_cur,
    float* __restrict__ h_nxt,
    const float* __restrict__ W_ih, const float* __restrict__ b_ih,
    const float* __restrict__ W_hh, const float* __restrict__ b_hh, int n) {
    __shared__ float lw[6][16 * HID];  // 24 KB
    __shared__ float lb[6][16];

    const int t  = threadIdx.x;
    const int q  = blockIdx.x & 3;
    const int j0 = q * 16;
    const int v  = (blockIdx.x >> 2) * 256 + t;

    {
        float4* dst = (float4*)lw;
        const float4* s0 = (const float4*)(W_ih + (size_t)(0   + j0) * HID);
        const float4* s1 = (const float4*)(W_ih + (size_t)(64  + j0) * HID);
        const float4* s2 = (const float4*)(W_ih + (size_t)(128 + j0) * HID);
        const float4* s3 = (const float4*)(W_hh + (size_t)(0   + j0) * HID);
        const float4* s4 = (const float4*)(W_hh + (size_t)(64  + j0) * HID);
        const float4* s5 = (const float4*)(W_hh + (size_t)(128 + j0) * HID);
        dst[0 * 256 + t] = s0[t];
        dst[1 * 256 + t] = s1[t];
        dst[2 * 256 + t] = s2[t];
        dst[3 * 256 + t] = s3[t];
        dst[4 * 256 + t] = s4[t];
        dst[5 * 256 + t] = s5[t];
        if (t < 16) {
            lb[0][t] = b_ih[0   + j0 + t];
            lb[1][t] = b_ih[64  + j0 + t];
            lb[2][t] = b_ih[128 + j0 + t];
            lb[3][t] = b_hh[0   + j0 + t];
            lb[4][t] = b_hh[64  + j0 + t];
            lb[5][t] = b_hh[128 + j0 + t];
        }
    }
    __syncthreads();
    if (v >= n) return;

    float4 a4[16], h4[16];
    const float4* ap = (const float4*)(agg + (size_t)v * HID);
    const float*  hrow = h_cur + (size_t)v * HID;
    const float4* hp = (const float4*)hrow;
#pragma unroll
    for (int k = 0; k < 16; k++) { a4[k] = ap[k]; h4[k] = hp[k]; }

    float* orow = h_nxt + (size_t)v * HID;
#pragma unroll 1
    for (int jg = 0; jg < 4; jg++) {
        float outv[4];
#pragma unroll
        for (int jj = 0; jj < 4; jj++) {
            const int jl = jg * 4 + jj;
            float ir = lb[0][jl], iz = lb[1][jl], in_ = lb[2][jl];
            float hr = lb[3][jl], hz = lb[4][jl], hn  = lb[5][jl];
            const float4* w0 = (const float4*)&lw[0][jl * HID];
            const float4* w1 = (const float4*)&lw[1][jl * HID];
            const float4* w2 = (const float4*)&lw[2][jl * HID];
            const float4* w3 = (const float4*)&lw[3][jl * HID];
            const float4* w4 = (const float4*)&lw[4][jl * HID];
            const float4* w5 = (const float4*)&lw[5][jl * HID];
#pragma unroll
            for (int k = 0; k < 16; k++) {
                float4 av = a4[k], hv = h4[k];
                float4 w;
                w = w0[k]; ir  += w.x * av.x + w.y * av.y + w.z * av.z + w.w * av.w;
                w = w1[k]; iz  += w.x * av.x + w.y * av.y + w.z * av.z + w.w * av.w;
                w = w2[k]; in_ += w.x * av.x + w.y * av.y + w.z * av.z + w.w * av.w;
                w = w3[k]; hr  += w.x * hv.x + w.y * hv.y + w.z * hv.z + w.w * hv.w;
                w = w4[k]; hz  += w.x * hv.x + w.y * hv.y + w.z * hv.z + w.w * hv.w;
                w = w5[k]; hn  += w.x * hv.x + w.y * hv.y + w.z * hv.z + w.w * hv.w;
            }
            float r  = 1.f / (1.f + expf(-(ir + hr)));
            float z  = 1.f / (1.f + expf(-(iz + hz)));
            float nn = tanhf(in_ + r * hn);
            float hold = hrow[j0 + jl];  // old h (read-only buffer), static addr
            outv[jj] = (1.f - z) * nn + z * hold;
        }
        *(float4*)(orow + j0 + jg * 4) = make_float4(outv[0], outv[1], outv[2], outv[3]);
    }
}

// ---------------- monolithic GRU fallback (in-place, race-free) ----------------
// Used only if ws_size can't fit the ping-pong buffer. Slow but correct.

__global__ __launch_bounds__(256) void gru_mono_kernel(
    const float* __restrict__ agg, float* __restrict__ h,
    const float* __restrict__ W_ih, const float* __restrict__ b_ih,
    const float* __restrict__ W_hh, const float* __restrict__ b_hh, int n) {
    int v = blockIdx.x * blockDim.x + threadIdx.x;
    if (v >= n) return;

    float4 a4[16], h4[16];
    const float4* ap = (const float4*)(agg + (size_t)v * HID);
    float* hrow = h + (size_t)v * HID;
    const float4* hp = (const float4*)hrow;
#pragma unroll
    for (int k = 0; k < 16; k++) { a4[k] = ap[k]; h4[k] = hp[k]; }

#pragma unroll 1
    for (int jg = 0; jg < 16; jg++) {
        float4 hold = *(const float4*)(hrow + jg * 4);
        float hops[4] = {hold.x, hold.y, hold.z, hold.w};
        float outv[4];
#pragma unroll
        for (int jj = 0; jj < 4; jj++) {
            int j = jg * 4 + jj;
            float ir = b_ih[j], iz = b_ih[HID + j], in_ = b_ih[2 * HID + j];
            float hr = b_hh[j], hz = b_hh[HID + j], hn  = b_hh[2 * HID + j];
            const float4* wir = (const float4*)(W_ih + (size_t)j * HID);
            const float4* wiz = (const float4*)(W_ih + (size_t)(HID + j) * HID);
            const float4* win = (const float4*)(W_ih + (size_t)(2 * HID + j) * HID);
            const float4* whr = (const float4*)(W_hh + (size_t)j * HID);
            const float4* whz = (const float4*)(W_hh + (size_t)(HID + j) * HID);
            const float4* whn = (const float4*)(W_hh + (size_t)(2 * HID + j) * HID);
#pragma unroll
            for (int k = 0; k < 16; k++) {
                float4 av = a4[k], hv = h4[k];
                float4 w;
                w = wir[k]; ir  += w.x * av.x + w.y * av.y + w.z * av.z + w.w * av.w;
                w = wiz[k]; iz  += w.x * av.x + w.y * av.y + w.z * av.z + w.w * av.w;
                w = win[k]; in_ += w.x * av.x + w.y * av.y + w.z * av.z + w.w * av.w;
                w = whr[k]; hr  += w.x * hv.x + w.y * hv.y + w.z * hv.z + w.w * hv.w;
                w = whz[k]; hz  += w.x * hv.x + w.y * hv.y + w.z * hv.z + w.w * hv.w;
                w = whn[k]; hn  += w.x * hv.x + w.y * hv.y + w.z * hv.z + w.w * hv.w;
            }
            float r  = 1.f / (1.f + expf(-(ir + hr)));
            float z  = 1.f / (1.f + expf(-(iz + hz)));
            float nn = tanhf(in_ + r * hn);
            outv[jj] = (1.f - z) * nn + z * hops[jj];
        }
        *(float4*)(hrow + jg * 4) = make_float4(outv[0], outv[1], outv[2], outv[3]);
    }
}

// ---------------- output projection ----------------

__global__ __launch_bounds__(256) void out_kernel(
    const float* __restrict__ h, const float* __restrict__ W_out,
    const float* __restrict__ b_out, float* __restrict__ out, int n) {
    int v = blockIdx.x * blockDim.x + threadIdx.x;
    if (v >= n) return;
    float4 h4[16];
    const float4* hp = (const float4*)(h + (size_t)v * HID);
#pragma unroll
    for (int k = 0; k < 16; k++) h4[k] = hp[k];
    float* orow = out + (size_t)v * HID;
#pragma unroll 1
    for (int jg = 0; jg < 16; jg++) {
        float acc[4];
#pragma unroll
        for (int jj = 0; jj < 4; jj++) {
            int j = jg * 4 + jj;
            float a = b_out[j];
            const float4* w = (const float4*)(W_out + (size_t)j * HID);
#pragma unroll
            for (int k = 0; k < 16; k++) {
                float4 wv = w[k], hv = h4[k];
                a += wv.x * hv.x + wv.y * hv.y + wv.z * hv.z + wv.w * hv.w;
            }
            acc[jj] = a;
        }
        *(float4*)(orow + jg * 4) = make_float4(acc[0], acc[1], acc[2], acc[3]);
    }
}

// ---------------- launch ----------------

extern "C" void kernel_launch(void* const* d_in, const int* in_sizes, int n_in,
                              void* d_out, int out_size, void* d_ws, size_t ws_size,
                              hipStream_t stream) {
    const float* x     = (const float*)d_in[0];
    const int*   ei    = (const int*)d_in[1];
    const float* W_in  = (const float*)d_in[2];
    const float* b_in  = (const float*)d_in[3];
    const float* W_t1  = (const float*)d_in[4];
    const float* b_t1  = (const float*)d_in[5];
    const float* W_t2  = (const float*)d_in[6];
    const float* b_t2  = (const float*)d_in[7];
    const float* W_ih  = (const float*)d_in[8];
    const float* b_ih  = (const float*)d_in[9];
    const float* W_hh  = (const float*)d_in[10];
    const float* b_hh  = (const float*)d_in[11];
    const float* W_out = (const float*)d_in[12];
    const float* b_out = (const float*)d_in[13];
    float* out = (float*)d_out;

    const int n = in_sizes[0] / IN_DIM;  // 100000
    const int e = in_sizes[1] / 2;       // 1000000
    const int* row = ei;
    const int* col = ei + e;

    const size_t hbytes = (size_t)n * HID * sizeof(float);
    const size_t need_pingpong =
        3 * hbytes + 4 * (size_t)n * sizeof(int) + SCAN_B * sizeof(int)
        + (size_t)e * sizeof(int) + 1024;
    const bool pingpong = (ws_size >= need_pingpong);

    char* ws = (char*)d_ws;
    float* h0  = (float*)ws;  ws += hbytes;
    float* h1  = nullptr;
    if (pingpong) { h1 = (float*)ws; ws += hbytes; }
    float* agg = (float*)ws;  ws += hbytes;
    float* tau = (float*)ws;  ws += (size_t)n * sizeof(float);
    int* deg       = (int*)ws;  ws += (size_t)n * sizeof(int);
    int* row_start = (int*)ws;  ws += (size_t)n * sizeof(int);
    int* cursor    = (int*)ws;  ws += (size_t)n * sizeof(int);
    int* blk       = (int*)ws;  ws += SCAN_B * sizeof(int);
    int* cols      = (int*)ws;  ws += (size_t)e * sizeof(int);

    const int nb = (n + SCAN_B - 1) / SCAN_B;
    const int ntile = (n + 255) / 256;

    zero_int_kernel<<<(n + 255) / 256, 256, 0, stream>>>(deg, n);
    count_deg_kernel<<<(e + 255) / 256, 256, 0, stream>>>(row, deg, e, n);
    block_sum_kernel<<<nb, SCAN_B, 0, stream>>>(deg, blk, n);
    scan_blk_kernel<<<1, SCAN_B, 0, stream>>>(blk, nb);
    scan_final_kernel<<<nb, SCAN_B, 0, stream>>>(deg, blk, row_start, cursor, n);
    fill_csr_kernel<<<(e + 255) / 256, 256, 0, stream>>>(row, col, cursor, cols, e, n);

    init_kernel<<<ntile, 256, 0, stream>>>(x, W_in, b_in, W_t1, b_t1,
                                           W_t2, b_t2, h0, tau, n);
    if (pingpong) {
        float* hc = h0;
        float* hn2 = h1;
        for (int it = 0; it < 5; ++it) {
            aggregate_kernel<<<((n * 16) + 255) / 256, 256, 0, stream>>>(
                hc, tau, row_start, deg, cols, agg, n);
            gru_kernel<<<ntile * 4, 256, 0, stream>>>(agg, hc, hn2,
                                                      W_ih, b_ih, W_hh, b_hh, n);
            float* tmp = hc; hc = hn2; hn2 = tmp;
        }
        out_kernel<<<ntile, 256, 0, stream>>>(hc, W_out, b_out, out, n);
    } else {
        for (int it = 0; it < 5; ++it) {
            aggregate_kernel<<<((n * 16) + 255) / 256, 256, 0, stream>>>(
                h0, tau, row_start, deg, cols, agg, n);
            gru_mono_kernel<<<ntile, 256, 0, stream>>>(agg, h0,
                                                       W_ih, b_ih, W_hh, b_hh, n);
        }
        out_kernel<<<ntile, 256, 0, stream>>>(h0, W_out, b_out, out, n);
    }
}

// Round 6
// 3201.479 us; speedup vs baseline: 6.1796x; 6.1796x over previous
//
#include <hip/hip_runtime.h>

#define HID 64
#define IN_DIM 128
#define TAU_DIM 8
#define SCAN_B 1024

// ---------------- CSR build ----------------
// All index inputs are bounds-guarded: malformed edge data must produce a
// wrong answer (validation failure), never a device memory fault.

__global__ void zero_int_kernel(int* __restrict__ p, int n) {
    int i = blockIdx.x * blockDim.x + threadIdx.x;
    if (i < n) p[i] = 0;
}

__global__ void count_deg_kernel(const int* __restrict__ row, int* __restrict__ deg,
                                 int e, int n) {
    int i = blockIdx.x * blockDim.x + threadIdx.x;
    if (i < e) {
        int r = row[i];
        if ((unsigned)r < (unsigned)n) atomicAdd(&deg[r], 1);
    }
}

__global__ void block_sum_kernel(const int* __restrict__ deg, int* __restrict__ blk, int n) {
    __shared__ int s[SCAN_B];
    int i = blockIdx.x * SCAN_B + threadIdx.x;
    s[threadIdx.x] = (i < n) ? deg[i] : 0;
    __syncthreads();
    for (int off = SCAN_B / 2; off > 0; off >>= 1) {
        if (threadIdx.x < off) s[threadIdx.x] += s[threadIdx.x + off];
        __syncthreads();
    }
    if (threadIdx.x == 0) blk[blockIdx.x] = s[0];
}

__global__ void scan_blk_kernel(int* __restrict__ blk, int nb) {
    __shared__ int s[SCAN_B];
    int v = (threadIdx.x < nb) ? blk[threadIdx.x] : 0;
    s[threadIdx.x] = v;
    __syncthreads();
    for (int off = 1; off < SCAN_B; off <<= 1) {
        int t = (threadIdx.x >= off) ? s[threadIdx.x - off] : 0;
        __syncthreads();
        s[threadIdx.x] += t;
        __syncthreads();
    }
    if (threadIdx.x < nb) blk[threadIdx.x] = s[threadIdx.x] - v;  // exclusive
}

__global__ void scan_final_kernel(const int* __restrict__ deg, const int* __restrict__ blk,
                                  int* __restrict__ row_start, int* __restrict__ cursor, int n) {
    __shared__ int s[SCAN_B];
    int i = blockIdx.x * SCAN_B + threadIdx.x;
    int v = (i < n) ? deg[i] : 0;
    s[threadIdx.x] = v;
    __syncthreads();
    for (int off = 1; off < SCAN_B; off <<= 1) {
        int t = (threadIdx.x >= off) ? s[threadIdx.x - off] : 0;
        __syncthreads();
        s[threadIdx.x] += t;
        __syncthreads();
    }
    if (i < n) {
        int excl = s[threadIdx.x] - v + blk[blockIdx.x];
        row_start[i] = excl;
        cursor[i]    = excl;
    }
}

__global__ void fill_csr_kernel(const int* __restrict__ row, const int* __restrict__ col,
                                int* __restrict__ cursor, int* __restrict__ cols,
                                int e, int n) {
    int i = blockIdx.x * blockDim.x + threadIdx.x;
    if (i < e) {
        int r = row[i];
        if ((unsigned)r < (unsigned)n) {
            int c = col[i];
            if ((unsigned)c >= (unsigned)n) c = 0;  // never store an OOB index
            int p = atomicAdd(&cursor[r], 1);
            cols[p] = c;
        }
    }
}

// ---------------- init: h0 = relu(x@W_in.T+b), tau = mean(sigmoid(relu(x@W_t1.T+b)@W_t2.T+b)) ----------------

__global__ __launch_bounds__(256) void init_kernel(
    const float* __restrict__ x,
    const float* __restrict__ W_in, const float* __restrict__ b_in,
    const float* __restrict__ W_t1, const float* __restrict__ b_t1,
    const float* __restrict__ W_t2, const float* __restrict__ b_t2,
    float* __restrict__ h, float* __restrict__ tau, int n) {
    int v = blockIdx.x * blockDim.x + threadIdx.x;
    if (v >= n) return;

    float4 xr[32];
    const float4* xp = (const float4*)(x + (size_t)v * IN_DIM);
#pragma unroll
    for (int k = 0; k < 32; k++) xr[k] = xp[k];

    float* hv = h + (size_t)v * HID;
#pragma unroll 1
    for (int jg = 0; jg < 16; jg++) {
        int j = jg * 4;
        float a0 = b_in[j], a1 = b_in[j + 1], a2 = b_in[j + 2], a3 = b_in[j + 3];
        const float4* w0 = (const float4*)(W_in + (size_t)(j + 0) * IN_DIM);
        const float4* w1 = (const float4*)(W_in + (size_t)(j + 1) * IN_DIM);
        const float4* w2 = (const float4*)(W_in + (size_t)(j + 2) * IN_DIM);
        const float4* w3 = (const float4*)(W_in + (size_t)(j + 3) * IN_DIM);
#pragma unroll
        for (int k = 0; k < 32; k++) {
            float4 xv = xr[k];
            float4 wa = w0[k], wb = w1[k], wc = w2[k], wd = w3[k];
            a0 += wa.x * xv.x + wa.y * xv.y + wa.z * xv.z + wa.w * xv.w;
            a1 += wb.x * xv.x + wb.y * xv.y + wb.z * xv.z + wb.w * xv.w;
            a2 += wc.x * xv.x + wc.y * xv.y + wc.z * xv.z + wc.w * xv.w;
            a3 += wd.x * xv.x + wd.y * xv.y + wd.z * xv.z + wd.w * xv.w;
        }
        *(float4*)(hv + j) = make_float4(fmaxf(a0, 0.f), fmaxf(a1, 0.f),
                                         fmaxf(a2, 0.f), fmaxf(a3, 0.f));
    }

    float t_acc[TAU_DIM];
#pragma unroll
    for (int m = 0; m < TAU_DIM; m++) t_acc[m] = b_t2[m];

#pragma unroll 1
    for (int jg = 0; jg < 16; jg++) {
        int j = jg * 4;
        float a0 = b_t1[j], a1 = b_t1[j + 1], a2 = b_t1[j + 2], a3 = b_t1[j + 3];
        const float4* w0 = (const float4*)(W_t1 + (size_t)(j + 0) * IN_DIM);
        const float4* w1 = (const float4*)(W_t1 + (size_t)(j + 1) * IN_DIM);
        const float4* w2 = (const float4*)(W_t1 + (size_t)(j + 2) * IN_DIM);
        const float4* w3 = (const float4*)(W_t1 + (size_t)(j + 3) * IN_DIM);
#pragma unroll
        for (int k = 0; k < 32; k++) {
            float4 xv = xr[k];
            float4 wa = w0[k], wb = w1[k], wc = w2[k], wd = w3[k];
            a0 += wa.x * xv.x + wa.y * xv.y + wa.z * xv.z + wa.w * xv.w;
            a1 += wb.x * xv.x + wb.y * xv.y + wb.z * xv.z + wb.w * xv.w;
            a2 += wc.x * xv.x + wc.y * xv.y + wc.z * xv.z + wc.w * xv.w;
            a3 += wd.x * xv.x + wd.y * xv.y + wd.z * xv.z + wd.w * xv.w;
        }
        a0 = fmaxf(a0, 0.f); a1 = fmaxf(a1, 0.f); a2 = fmaxf(a2, 0.f); a3 = fmaxf(a3, 0.f);
#pragma unroll
        for (int m = 0; m < TAU_DIM; m++) {
            t_acc[m] += W_t2[(size_t)m * HID + j]     * a0
                      + W_t2[(size_t)m * HID + j + 1] * a1
                      + W_t2[(size_t)m * HID + j + 2] * a2
                      + W_t2[(size_t)m * HID + j + 3] * a3;
        }
    }
    float tsum = 0.f;
#pragma unroll
    for (int m = 0; m < TAU_DIM; m++) tsum += 1.f / (1.f + expf(-t_acc[m]));
    tau[v] = tsum * (1.f / TAU_DIM);
}

// ---------------- aggregate: agg[v] = tau[v] * sum_e |h[v]-h[col[e]]| ----------------

__global__ __launch_bounds__(256) void aggregate_kernel(
    const float* __restrict__ h, const float* __restrict__ tau,
    const int* __restrict__ row_start, const int* __restrict__ deg,
    const int* __restrict__ cols, float* __restrict__ agg, int n) {
    int t = blockIdx.x * blockDim.x + threadIdx.x;
    int v = t >> 4;
    if (v >= n) return;
    int c4 = (t & 15) * 4;

    float4 hv = *(const float4*)(h + (size_t)v * HID + c4);
    float4 s0 = make_float4(0.f, 0.f, 0.f, 0.f);
    float4 s1 = make_float4(0.f, 0.f, 0.f, 0.f);
    int st = row_start[v];
    int d  = deg[v];
    int i = 0;
    for (; i + 1 < d; i += 2) {
        int c0 = cols[st + i];
        int c1 = cols[st + i + 1];
        float4 hc0 = *(const float4*)(h + (size_t)c0 * HID + c4);
        float4 hc1 = *(const float4*)(h + (size_t)c1 * HID + c4);
        s0.x += fabsf(hv.x - hc0.x);
        s0.y += fabsf(hv.y - hc0.y);
        s0.z += fabsf(hv.z - hc0.z);
        s0.w += fabsf(hv.w - hc0.w);
        s1.x += fabsf(hv.x - hc1.x);
        s1.y += fabsf(hv.y - hc1.y);
        s1.z += fabsf(hv.z - hc1.z);
        s1.w += fabsf(hv.w - hc1.w);
    }
    if (i < d) {
        int c = cols[st + i];
        float4 hc = *(const float4*)(h + (size_t)c * HID + c4);
        s0.x += fabsf(hv.x - hc.x);
        s0.y += fabsf(hv.y - hc.y);
        s0.z += fabsf(hv.z - hc.z);
        s0.w += fabsf(hv.w - hc.w);
    }
    float tv = tau[v];
    *(float4*)(agg + (size_t)v * HID + c4) =
        make_float4((s0.x + s1.x) * tv, (s0.y + s1.y) * tv,
                    (s0.z + s1.z) * tv, (s0.w + s1.w) * tv);
}

// ---------------- GRU cell, half-split, ping-pong (race-free, spill-free) ----------------
// blockIdx.x = (node_tile << 1) | half. Each thread = one node, computes
// outputs j in [half*32, half*32+32). Reads h_cur, writes h_nxt (ping-pong:
// no cross-block race). The half's 192 weight rows (48 KB) + biases staged
// in LDS; weight reads are same-address broadcasts (conflict-free).
// REGISTER DISCIPLINE (round-5 spill post-mortem): outputs computed ONE at a
// time (#pragma unroll 1) so only 6 accumulators are live on top of the
// 128-reg a4/h4 arrays. Round 5's 4-way output unroll hit the 256-VGPR cap
// and spilled a4/h4 to scratch (FETCH_SIZE 4 GB/dispatch, 5x regression).

__global__ __launch_bounds__(256) void gru_kernel(
    const float* __restrict__ agg, const float* __restrict__ h_cur,
    float* __restrict__ h_nxt,
    const float* __restrict__ W_ih, const float* __restrict__ b_ih,
    const float* __restrict__ W_hh, const float* __restrict__ b_hh, int n) {
    __shared__ float lw[6 * 32 * HID];  // 48 KB: 6 gate-chunks x 32 rows x 64
    __shared__ float lb[6][32];

    const int t  = threadIdx.x;
    const int j0 = (blockIdx.x & 1) * 32;
    const int v  = (blockIdx.x >> 1) * 256 + t;

    // stage: 6 chunks, each 32 contiguous rows of 64 floats = 512 float4
    {
        float4* dst = (float4*)lw;
        const float4* s0 = (const float4*)(W_ih + (size_t)(0   + j0) * HID);
        const float4* s1 = (const float4*)(W_ih + (size_t)(64  + j0) * HID);
        const float4* s2 = (const float4*)(W_ih + (size_t)(128 + j0) * HID);
        const float4* s3 = (const float4*)(W_hh + (size_t)(0   + j0) * HID);
        const float4* s4 = (const float4*)(W_hh + (size_t)(64  + j0) * HID);
        const float4* s5 = (const float4*)(W_hh + (size_t)(128 + j0) * HID);
#pragma unroll
        for (int r = 0; r < 2; r++) {
            dst[0 * 512 + r * 256 + t] = s0[r * 256 + t];
            dst[1 * 512 + r * 256 + t] = s1[r * 256 + t];
            dst[2 * 512 + r * 256 + t] = s2[r * 256 + t];
            dst[3 * 512 + r * 256 + t] = s3[r * 256 + t];
            dst[4 * 512 + r * 256 + t] = s4[r * 256 + t];
            dst[5 * 512 + r * 256 + t] = s5[r * 256 + t];
        }
        if (t < 32) {
            lb[0][t] = b_ih[0   + j0 + t];
            lb[1][t] = b_ih[64  + j0 + t];
            lb[2][t] = b_ih[128 + j0 + t];
            lb[3][t] = b_hh[0   + j0 + t];
            lb[4][t] = b_hh[64  + j0 + t];
            lb[5][t] = b_hh[128 + j0 + t];
        }
    }
    __syncthreads();
    if (v >= n) return;

    float4 a4[16], h4[16];
    const float4* ap = (const float4*)(agg + (size_t)v * HID);
    const float*  hrow = h_cur + (size_t)v * HID;
    const float4* hp = (const float4*)hrow;
#pragma unroll
    for (int k = 0; k < 16; k++) { a4[k] = ap[k]; h4[k] = hp[k]; }

    float* orow = h_nxt + (size_t)v * HID + j0;
#pragma unroll 1
    for (int jl = 0; jl < 32; jl++) {
        float ir = lb[0][jl], iz = lb[1][jl], in_ = lb[2][jl];
        float hr = lb[3][jl], hz = lb[4][jl], hn  = lb[5][jl];
        const float4* w0 = (const float4*)&lw[0 * 2048 + jl * HID];
        const float4* w1 = (const float4*)&lw[1 * 2048 + jl * HID];
        const float4* w2 = (const float4*)&lw[2 * 2048 + jl * HID];
        const float4* w3 = (const float4*)&lw[3 * 2048 + jl * HID];
        const float4* w4 = (const float4*)&lw[4 * 2048 + jl * HID];
        const float4* w5 = (const float4*)&lw[5 * 2048 + jl * HID];
#pragma unroll
        for (int k = 0; k < 16; k++) {
            float4 av = a4[k], hv = h4[k];
            float4 w;
            w = w0[k]; ir  += w.x * av.x + w.y * av.y + w.z * av.z + w.w * av.w;
            w = w1[k]; iz  += w.x * av.x + w.y * av.y + w.z * av.z + w.w * av.w;
            w = w2[k]; in_ += w.x * av.x + w.y * av.y + w.z * av.z + w.w * av.w;
            w = w3[k]; hr  += w.x * hv.x + w.y * hv.y + w.z * hv.z + w.w * hv.w;
            w = w4[k]; hz  += w.x * hv.x + w.y * hv.y + w.z * hv.z + w.w * hv.w;
            w = w5[k]; hn  += w.x * hv.x + w.y * hv.y + w.z * hv.z + w.w * hv.w;
        }
        float r  = 1.f / (1.f + expf(-(ir + hr)));
        float z  = 1.f / (1.f + expf(-(iz + hz)));
        float nn = tanhf(in_ + r * hn);
        float hold = hrow[j0 + jl];  // old h, read-only buffer
        orow[jl] = (1.f - z) * nn + z * hold;
    }
}

// ---------------- monolithic GRU fallback (in-place, race-free) ----------------
// Used only if ws_size can't fit the ping-pong buffer. Slow but correct.

__global__ __launch_bounds__(256) void gru_mono_kernel(
    const float* __restrict__ agg, float* __restrict__ h,
    const float* __restrict__ W_ih, const float* __restrict__ b_ih,
    const float* __restrict__ W_hh, const float* __restrict__ b_hh, int n) {
    int v = blockIdx.x * blockDim.x + threadIdx.x;
    if (v >= n) return;

    float4 a4[16], h4[16];
    const float4* ap = (const float4*)(agg + (size_t)v * HID);
    float* hrow = h + (size_t)v * HID;
    const float4* hp = (const float4*)hrow;
#pragma unroll
    for (int k = 0; k < 16; k++) { a4[k] = ap[k]; h4[k] = hp[k]; }

#pragma unroll 1
    for (int jg = 0; jg < 16; jg++) {
        float4 hold = *(const float4*)(hrow + jg * 4);
        float hops[4] = {hold.x, hold.y, hold.z, hold.w};
        float outv[4];
#pragma unroll
        for (int jj = 0; jj < 4; jj++) {
            int j = jg * 4 + jj;
            float ir = b_ih[j], iz = b_ih[HID + j], in_ = b_ih[2 * HID + j];
            float hr = b_hh[j], hz = b_hh[HID + j], hn  = b_hh[2 * HID + j];
            const float4* wir = (const float4*)(W_ih + (size_t)j * HID);
            const float4* wiz = (const float4*)(W_ih + (size_t)(HID + j) * HID);
            const float4* win = (const float4*)(W_ih + (size_t)(2 * HID + j) * HID);
            const float4* whr = (const float4*)(W_hh + (size_t)j * HID);
            const float4* whz = (const float4*)(W_hh + (size_t)(HID + j) * HID);
            const float4* whn = (const float4*)(W_hh + (size_t)(2 * HID + j) * HID);
#pragma unroll
            for (int k = 0; k < 16; k++) {
                float4 av = a4[k], hv = h4[k];
                float4 w;
                w = wir[k]; ir  += w.x * av.x + w.y * av.y + w.z * av.z + w.w * av.w;
                w = wiz[k]; iz  += w.x * av.x + w.y * av.y + w.z * av.z + w.w * av.w;
                w = win[k]; in_ += w.x * av.x + w.y * av.y + w.z * av.z + w.w * av.w;
                w = whr[k]; hr  += w.x * hv.x + w.y * hv.y + w.z * hv.z + w.w * hv.w;
                w = whz[k]; hz  += w.x * hv.x + w.y * hv.y + w.z * hv.z + w.w * hv.w;
                w = whn[k]; hn  += w.x * hv.x + w.y * hv.y + w.z * hv.z + w.w * hv.w;
            }
            float r  = 1.f / (1.f + expf(-(ir + hr)));
            float z  = 1.f / (1.f + expf(-(iz + hz)));
            float nn = tanhf(in_ + r * hn);
            outv[jj] = (1.f - z) * nn + z * hops[jj];
        }
        *(float4*)(hrow + jg * 4) = make_float4(outv[0], outv[1], outv[2], outv[3]);
    }
}

// ---------------- output projection ----------------

__global__ __launch_bounds__(256) void out_kernel(
    const float* __restrict__ h, const float* __restrict__ W_out,
    const float* __restrict__ b_out, float* __restrict__ out, int n) {
    int v = blockIdx.x * blockDim.x + threadIdx.x;
    if (v >= n) return;
    float4 h4[16];
    const float4* hp = (const float4*)(h + (size_t)v * HID);
#pragma unroll
    for (int k = 0; k < 16; k++) h4[k] = hp[k];
    float* orow = out + (size_t)v * HID;
#pragma unroll 1
    for (int jg = 0; jg < 16; jg++) {
        float acc[4];
#pragma unroll
        for (int jj = 0; jj < 4; jj++) {
            int j = jg * 4 + jj;
            float a = b_out[j];
            const float4* w = (const float4*)(W_out + (size_t)j * HID);
#pragma unroll
            for (int k = 0; k < 16; k++) {
                float4 wv = w[k], hv = h4[k];
                a += wv.x * hv.x + wv.y * hv.y + wv.z * hv.z + wv.w * hv.w;
            }
            acc[jj] = a;
        }
        *(float4*)(orow + jg * 4) = make_float4(acc[0], acc[1], acc[2], acc[3]);
    }
}

// ---------------- launch ----------------

extern "C" void kernel_launch(void* const* d_in, const int* in_sizes, int n_in,
                              void* d_out, int out_size, void* d_ws, size_t ws_size,
                              hipStream_t stream) {
    const float* x     = (const float*)d_in[0];
    const int*   ei    = (const int*)d_in[1];
    const float* W_in  = (const float*)d_in[2];
    const float* b_in  = (const float*)d_in[3];
    const float* W_t1  = (const float*)d_in[4];
    const float* b_t1  = (const float*)d_in[5];
    const float* W_t2  = (const float*)d_in[6];
    const float* b_t2  = (const float*)d_in[7];
    const float* W_ih  = (const float*)d_in[8];
    const float* b_ih  = (const float*)d_in[9];
    const float* W_hh  = (const float*)d_in[10];
    const float* b_hh  = (const float*)d_in[11];
    const float* W_out = (const float*)d_in[12];
    const float* b_out = (const float*)d_in[13];
    float* out = (float*)d_out;

    const int n = in_sizes[0] / IN_DIM;  // 100000
    const int e = in_sizes[1] / 2;       // 1000000
    const int* row = ei;
    const int* col = ei + e;

    const size_t hbytes = (size_t)n * HID * sizeof(float);
    const size_t need_pingpong =
        3 * hbytes + 4 * (size_t)n * sizeof(int) + SCAN_B * sizeof(int)
        + (size_t)e * sizeof(int) + 1024;
    const bool pingpong = (ws_size >= need_pingpong);

    char* ws = (char*)d_ws;
    float* h0  = (float*)ws;  ws += hbytes;
    float* h1  = nullptr;
    if (pingpong) { h1 = (float*)ws; ws += hbytes; }
    float* agg = (float*)ws;  ws += hbytes;
    float* tau = (float*)ws;  ws += (size_t)n * sizeof(float);
    int* deg       = (int*)ws;  ws += (size_t)n * sizeof(int);
    int* row_start = (int*)ws;  ws += (size_t)n * sizeof(int);
    int* cursor    = (int*)ws;  ws += (size_t)n * sizeof(int);
    int* blk       = (int*)ws;  ws += SCAN_B * sizeof(int);
    int* cols      = (int*)ws;  ws += (size_t)e * sizeof(int);

    const int nb = (n + SCAN_B - 1) / SCAN_B;
    const int ntile = (n + 255) / 256;

    zero_int_kernel<<<(n + 255) / 256, 256, 0, stream>>>(deg, n);
    count_deg_kernel<<<(e + 255) / 256, 256, 0, stream>>>(row, deg, e, n);
    block_sum_kernel<<<nb, SCAN_B, 0, stream>>>(deg, blk, n);
    scan_blk_kernel<<<1, SCAN_B, 0, stream>>>(blk, nb);
    scan_final_kernel<<<nb, SCAN_B, 0, stream>>>(deg, blk, row_start, cursor, n);
    fill_csr_kernel<<<(e + 255) / 256, 256, 0, stream>>>(row, col, cursor, cols, e, n);

    init_kernel<<<ntile, 256, 0, stream>>>(x, W_in, b_in, W_t1, b_t1,
                                           W_t2, b_t2, h0, tau, n);
    if (pingpong) {
        float* hc = h0;
        float* hn2 = h1;
        for (int it = 0; it < 5; ++it) {
            aggregate_kernel<<<((n * 16) + 255) / 256, 256, 0, stream>>>(
                hc, tau, row_start, deg, cols, agg, n);
            gru_kernel<<<ntile * 2, 256, 0, stream>>>(agg, hc, hn2,
                                                      W_ih, b_ih, W_hh, b_hh, n);
            float* tmp = hc; hc = hn2; hn2 = tmp;
        }
        out_kernel<<<ntile, 256, 0, stream>>>(hc, W_out, b_out, out, n);
    } else {
        for (int it = 0; it < 5; ++it) {
            aggregate_kernel<<<((n * 16) + 255) / 256, 256, 0, stream>>>(
                h0, tau, row_start, deg, cols, agg, n);
            gru_mono_kernel<<<ntile, 256, 0, stream>>>(agg, h0,
                                                       W_ih, b_ih, W_hh, b_hh, n);
        }
        out_kernel<<<ntile, 256, 0, stream>>>(h0, W_out, b_out, out, n);
    }
}

// Round 7
// 1500.706 us; speedup vs baseline: 13.1829x; 2.1333x over previous
//
#include <hip/hip_runtime.h>

#define HID 64
#define IN_DIM 128
#define TAU_DIM 8
#define SCAN_B 1024

#define KDIM 128        // X row = [agg(64) | h(64)]
#define NT 64           // nodes per GEMM block
#define JOUT 256        // padded gate outputs: [rz(128) | i_n(64) | h_n(64)]
#define XS_STRIDE 132   // 128 + 4 pad (f32 words)
#define WS_STRIDE 20    // 16 + 4 pad (f32 words)

// ---------------- CSR build (bounds-guarded) ----------------

__global__ void zero_int_kernel(int* __restrict__ p, int n) {
    int i = blockIdx.x * blockDim.x + threadIdx.x;
    if (i < n) p[i] = 0;
}

__global__ void count_deg_kernel(const int* __restrict__ row, int* __restrict__ deg,
                                 int e, int n) {
    int i = blockIdx.x * blockDim.x + threadIdx.x;
    if (i < e) {
        int r = row[i];
        if ((unsigned)r < (unsigned)n) atomicAdd(&deg[r], 1);
    }
}

__global__ void block_sum_kernel(const int* __restrict__ deg, int* __restrict__ blk, int n) {
    __shared__ int s[SCAN_B];
    int i = blockIdx.x * SCAN_B + threadIdx.x;
    s[threadIdx.x] = (i < n) ? deg[i] : 0;
    __syncthreads();
    for (int off = SCAN_B / 2; off > 0; off >>= 1) {
        if (threadIdx.x < off) s[threadIdx.x] += s[threadIdx.x + off];
        __syncthreads();
    }
    if (threadIdx.x == 0) blk[blockIdx.x] = s[0];
}

__global__ void scan_blk_kernel(int* __restrict__ blk, int nb) {
    __shared__ int s[SCAN_B];
    int v = (threadIdx.x < nb) ? blk[threadIdx.x] : 0;
    s[threadIdx.x] = v;
    __syncthreads();
    for (int off = 1; off < SCAN_B; off <<= 1) {
        int t = (threadIdx.x >= off) ? s[threadIdx.x - off] : 0;
        __syncthreads();
        s[threadIdx.x] += t;
        __syncthreads();
    }
    if (threadIdx.x < nb) blk[threadIdx.x] = s[threadIdx.x] - v;  // exclusive
}

__global__ void scan_final_kernel(const int* __restrict__ deg, const int* __restrict__ blk,
                                  int* __restrict__ row_start, int* __restrict__ cursor, int n) {
    __shared__ int s[SCAN_B];
    int i = blockIdx.x * SCAN_B + threadIdx.x;
    int v = (i < n) ? deg[i] : 0;
    s[threadIdx.x] = v;
    __syncthreads();
    for (int off = 1; off < SCAN_B; off <<= 1) {
        int t = (threadIdx.x >= off) ? s[threadIdx.x - off] : 0;
        __syncthreads();
        s[threadIdx.x] += t;
        __syncthreads();
    }
    if (i < n) {
        int excl = s[threadIdx.x] - v + blk[blockIdx.x];
        row_start[i] = excl;
        cursor[i]    = excl;
    }
}

__global__ void fill_csr_kernel(const int* __restrict__ row, const int* __restrict__ col,
                                int* __restrict__ cursor, int* __restrict__ cols,
                                int e, int n) {
    int i = blockIdx.x * blockDim.x + threadIdx.x;
    if (i < e) {
        int r = row[i];
        if ((unsigned)r < (unsigned)n) {
            int c = col[i];
            if ((unsigned)c >= (unsigned)n) c = 0;
            int p = atomicAdd(&cursor[r], 1);
            cols[p] = c;
        }
    }
}

// ---------------- weight repack: W2p [8 kchunks][256 rows][16 k], B2 [256] ----------------
// rows 0..127:  [W_ih[j] | W_hh[j]]      (r,z gates: pre-activations sum)
// rows 128..191:[W_ih[j] | 0]            (i_n)
// rows 192..255:[0 | W_hh[j-64]]         (h_n)

__global__ void prep_w2_kernel(const float* __restrict__ W_ih, const float* __restrict__ W_hh,
                               const float* __restrict__ b_ih, const float* __restrict__ b_hh,
                               float* __restrict__ W2p, float* __restrict__ B2) {
    int j = threadIdx.x;  // 256 threads, 1 block
    float b;
    if (j < 128)      b = b_ih[j] + b_hh[j];
    else if (j < 192) b = b_ih[j];
    else              b = b_hh[j - 64];
    B2[j] = b;
    for (int k = 0; k < KDIM; k++) {
        float v;
        if (j < 128)      v = (k < 64) ? W_ih[j * 64 + k] : W_hh[j * 64 + (k - 64)];
        else if (j < 192) v = (k < 64) ? W_ih[j * 64 + k] : 0.f;
        else              v = (k >= 64) ? W_hh[(j - 64) * 64 + (k - 64)] : 0.f;
        W2p[(size_t)(k >> 4) * (JOUT * 16) + j * 16 + (k & 15)] = v;
    }
}

// ---------------- init: h0 -> X1[.][64:128], tau ----------------

__global__ __launch_bounds__(256) void init_kernel(
    const float* __restrict__ x,
    const float* __restrict__ W_in, const float* __restrict__ b_in,
    const float* __restrict__ W_t1, const float* __restrict__ b_t1,
    const float* __restrict__ W_t2, const float* __restrict__ b_t2,
    float* __restrict__ X1, float* __restrict__ tau, int n) {
    int v = blockIdx.x * blockDim.x + threadIdx.x;
    if (v >= n) return;

    float4 xr[32];
    const float4* xp = (const float4*)(x + (size_t)v * IN_DIM);
#pragma unroll
    for (int k = 0; k < 32; k++) xr[k] = xp[k];

    float* hv = X1 + (size_t)v * KDIM + 64;
#pragma unroll 1
    for (int jg = 0; jg < 16; jg++) {
        int j = jg * 4;
        float a0 = b_in[j], a1 = b_in[j + 1], a2 = b_in[j + 2], a3 = b_in[j + 3];
        const float4* w0 = (const float4*)(W_in + (size_t)(j + 0) * IN_DIM);
        const float4* w1 = (const float4*)(W_in + (size_t)(j + 1) * IN_DIM);
        const float4* w2 = (const float4*)(W_in + (size_t)(j + 2) * IN_DIM);
        const float4* w3 = (const float4*)(W_in + (size_t)(j + 3) * IN_DIM);
#pragma unroll
        for (int k = 0; k < 32; k++) {
            float4 xv = xr[k];
            float4 wa = w0[k], wb = w1[k], wc = w2[k], wd = w3[k];
            a0 += wa.x * xv.x + wa.y * xv.y + wa.z * xv.z + wa.w * xv.w;
            a1 += wb.x * xv.x + wb.y * xv.y + wb.z * xv.z + wb.w * xv.w;
            a2 += wc.x * xv.x + wc.y * xv.y + wc.z * xv.z + wc.w * xv.w;
            a3 += wd.x * xv.x + wd.y * xv.y + wd.z * xv.z + wd.w * xv.w;
        }
        *(float4*)(hv + j) = make_float4(fmaxf(a0, 0.f), fmaxf(a1, 0.f),
                                         fmaxf(a2, 0.f), fmaxf(a3, 0.f));
    }

    float t_acc[TAU_DIM];
#pragma unroll
    for (int m = 0; m < TAU_DIM; m++) t_acc[m] = b_t2[m];

#pragma unroll 1
    for (int jg = 0; jg < 16; jg++) {
        int j = jg * 4;
        float a0 = b_t1[j], a1 = b_t1[j + 1], a2 = b_t1[j + 2], a3 = b_t1[j + 3];
        const float4* w0 = (const float4*)(W_t1 + (size_t)(j + 0) * IN_DIM);
        const float4* w1 = (const float4*)(W_t1 + (size_t)(j + 1) * IN_DIM);
        const float4* w2 = (const float4*)(W_t1 + (size_t)(j + 2) * IN_DIM);
        const float4* w3 = (const float4*)(W_t1 + (size_t)(j + 3) * IN_DIM);
#pragma unroll
        for (int k = 0; k < 32; k++) {
            float4 xv = xr[k];
            float4 wa = w0[k], wb = w1[k], wc = w2[k], wd = w3[k];
            a0 += wa.x * xv.x + wa.y * xv.y + wa.z * xv.z + wa.w * xv.w;
            a1 += wb.x * xv.x + wb.y * xv.y + wb.z * xv.z + wb.w * xv.w;
            a2 += wc.x * xv.x + wc.y * xv.y + wc.z * xv.z + wc.w * xv.w;
            a3 += wd.x * xv.x + wd.y * xv.y + wd.z * xv.z + wd.w * xv.w;
        }
        a0 = fmaxf(a0, 0.f); a1 = fmaxf(a1, 0.f); a2 = fmaxf(a2, 0.f); a3 = fmaxf(a3, 0.f);
#pragma unroll
        for (int m = 0; m < TAU_DIM; m++) {
            t_acc[m] += W_t2[(size_t)m * HID + j]     * a0
                      + W_t2[(size_t)m * HID + j + 1] * a1
                      + W_t2[(size_t)m * HID + j + 2] * a2
                      + W_t2[(size_t)m * HID + j + 3] * a3;
        }
    }
    float tsum = 0.f;
#pragma unroll
    for (int m = 0; m < TAU_DIM; m++) tsum += 1.f / (1.f + expf(-t_acc[m]));
    tau[v] = tsum * (1.f / TAU_DIM);
}

// ---------------- aggregate: X1[v][aoff..] = tau[v] * sum |h[v]-h[col]| (h at hoff) ----------------

__global__ __launch_bounds__(256) void aggregate_kernel(
    float* __restrict__ X1, const float* __restrict__ tau,
    const int* __restrict__ row_start, const int* __restrict__ deg,
    const int* __restrict__ cols, int n, int hoff, int aoff) {
    int t = blockIdx.x * blockDim.x + threadIdx.x;
    int v = t >> 4;
    if (v >= n) return;
    int c4 = (t & 15) * 4;

    float4 hv = *(const float4*)(X1 + (size_t)v * KDIM + hoff + c4);
    float4 s0 = make_float4(0.f, 0.f, 0.f, 0.f);
    float4 s1 = make_float4(0.f, 0.f, 0.f, 0.f);
    int st = row_start[v];
    int d  = deg[v];
    int i = 0;
    for (; i + 1 < d; i += 2) {
        int c0 = cols[st + i];
        int c1 = cols[st + i + 1];
        float4 hc0 = *(const float4*)(X1 + (size_t)c0 * KDIM + hoff + c4);
        float4 hc1 = *(const float4*)(X1 + (size_t)c1 * KDIM + hoff + c4);
        s0.x += fabsf(hv.x - hc0.x);
        s0.y += fabsf(hv.y - hc0.y);
        s0.z += fabsf(hv.z - hc0.z);
        s0.w += fabsf(hv.w - hc0.w);
        s1.x += fabsf(hv.x - hc1.x);
        s1.y += fabsf(hv.y - hc1.y);
        s1.z += fabsf(hv.z - hc1.z);
        s1.w += fabsf(hv.w - hc1.w);
    }
    if (i < d) {
        int c = cols[st + i];
        float4 hc = *(const float4*)(X1 + (size_t)c * KDIM + hoff + c4);
        s0.x += fabsf(hv.x - hc.x);
        s0.y += fabsf(hv.y - hc.y);
        s0.z += fabsf(hv.z - hc.z);
        s0.w += fabsf(hv.w - hc.w);
    }
    float tv = tau[v];
    *(float4*)(X1 + (size_t)v * KDIM + aoff + c4) =
        make_float4((s0.x + s1.x) * tv, (s0.y + s1.y) * tv,
                    (s0.z + s1.z) * tv, (s0.w + s1.w) * tv);
}

// ---------------- GRU as tiled GEMM + fused gating ----------------
// Block: 64 nodes x 256 gate-outs, K=128. Thread (tx=t&15, ty=t>>4) owns
// 4 nodes (ty*4..+4) x 16 outs (j = i*16+tx in each of 4 gate quadrants).
// X tile + W K-chunk in LDS (pads chosen for <=2-way bank aliasing = free).
// All 4 gate quadrants of col j land in the SAME thread -> gating is local.
// Reads X1[agg @ aoff | h @ hoff], writes h' into the (dead) agg columns.
// Register budget: 64 acc + 16 x + addressing ~ 110 mandatory (round-5/6
// post-mortem: never hold full per-node rows in VGPRs).

__global__ __launch_bounds__(256) void gru_gemm_kernel(
    float* __restrict__ X1, const float* __restrict__ W2p,
    const float* __restrict__ B2, int n, int hoff, int aoff) {
    __shared__ float xs[NT * XS_STRIDE];    // 33 KB
    __shared__ float wsh[JOUT * WS_STRIDE]; // 20 KB

    const int t  = threadIdx.x;
    const int tx = t & 15;
    const int ty = t >> 4;
    const int node0 = blockIdx.x * NT;

    // stage X tile: cols [0,64) <- agg (aoff), cols [64,128) <- h (hoff)
    {
        const int aoff4 = aoff >> 2, hoff4 = hoff >> 2;
#pragma unroll
        for (int i = 0; i < 8; i++) {
            int f4 = i * 256 + t;   // 0..2047
            int r  = f4 >> 5;       // tile row
            int c4 = f4 & 31;       // dest float4 col
            int src4 = (c4 < 16) ? (aoff4 + c4) : (hoff4 + (c4 - 16));
            float4 v = make_float4(0.f, 0.f, 0.f, 0.f);
            int node = node0 + r;
            if (node < n) v = *(const float4*)(X1 + (size_t)node * KDIM + src4 * 4);
            *(float4*)(xs + r * XS_STRIDE + c4 * 4) = v;
        }
    }

    float acc[4][4][4];  // [nd][gate-quad][i]; j = gb*64 + i*16 + tx
#pragma unroll
    for (int gb = 0; gb < 4; gb++)
#pragma unroll
        for (int i = 0; i < 4; i++) {
            float b = B2[gb * 64 + i * 16 + tx];
#pragma unroll
            for (int nd = 0; nd < 4; nd++) acc[nd][gb][i] = b;
        }

#pragma unroll 1
    for (int kc = 0; kc < 8; kc++) {
        __syncthreads();  // previous chunk consumed (also fences xs staging)
        {
            const float4* src = (const float4*)(W2p + (size_t)kc * (JOUT * 16));
#pragma unroll
            for (int i = 0; i < 4; i++) {
                int f4  = i * 256 + t;  // 0..1023
                int row = f4 >> 2;
                int k4  = f4 & 3;
                float4 v = src[f4];
                *(float4*)(wsh + row * WS_STRIDE + k4 * 4) = v;
            }
        }
        __syncthreads();
#pragma unroll 1
        for (int k4 = 0; k4 < 4; k4++) {
            float4 xv[4];
#pragma unroll
            for (int nd = 0; nd < 4; nd++)
                xv[nd] = *(const float4*)(xs + (ty * 4 + nd) * XS_STRIDE + kc * 16 + k4 * 4);
#pragma unroll
            for (int gb = 0; gb < 4; gb++)
#pragma unroll
                for (int i = 0; i < 4; i++) {
                    float4 w = *(const float4*)(wsh + (gb * 64 + i * 16 + tx) * WS_STRIDE + k4 * 4);
#pragma unroll
                    for (int nd = 0; nd < 4; nd++) {
                        acc[nd][gb][i] += w.x * xv[nd].x + w.y * xv[nd].y
                                        + w.z * xv[nd].z + w.w * xv[nd].w;
                    }
                }
        }
    }

    // fused gating epilogue: r=sig(q0), z=sig(q1), n=tanh(q2 + r*q3)
#pragma unroll
    for (int nd = 0; nd < 4; nd++) {
        int node = node0 + ty * 4 + nd;
        if (node < n) {
#pragma unroll
            for (int i = 0; i < 4; i++) {
                float r  = 1.f / (1.f + expf(-acc[nd][0][i]));
                float z  = 1.f / (1.f + expf(-acc[nd][1][i]));
                float nn = tanhf(acc[nd][2][i] + r * acc[nd][3][i]);
                float hold = xs[(ty * 4 + nd) * XS_STRIDE + 64 + i * 16 + tx];
                X1[(size_t)node * KDIM + aoff + i * 16 + tx] = (1.f - z) * nn + z * hold;
            }
        }
    }
}

// ---------------- output projection (h at hoff) ----------------

__global__ __launch_bounds__(256) void out_kernel(
    const float* __restrict__ X1, const float* __restrict__ W_out,
    const float* __restrict__ b_out, float* __restrict__ out, int n, int hoff) {
    int v = blockIdx.x * blockDim.x + threadIdx.x;
    if (v >= n) return;
    float4 h4[16];
    const float4* hp = (const float4*)(X1 + (size_t)v * KDIM + hoff);
#pragma unroll
    for (int k = 0; k < 16; k++) h4[k] = hp[k];
    float* orow = out + (size_t)v * HID;
#pragma unroll 1
    for (int jg = 0; jg < 16; jg++) {
        float acc[4];
#pragma unroll
        for (int jj = 0; jj < 4; jj++) {
            int j = jg * 4 + jj;
            float a = b_out[j];
            const float4* w = (const float4*)(W_out + (size_t)j * HID);
#pragma unroll
            for (int k = 0; k < 16; k++) {
                float4 wv = w[k], hv = h4[k];
                a += wv.x * hv.x + wv.y * hv.y + wv.z * hv.z + wv.w * hv.w;
            }
            acc[jj] = a;
        }
        *(float4*)(orow + jg * 4) = make_float4(acc[0], acc[1], acc[2], acc[3]);
    }
}

// ---------------- launch ----------------

extern "C" void kernel_launch(void* const* d_in, const int* in_sizes, int n_in,
                              void* d_out, int out_size, void* d_ws, size_t ws_size,
                              hipStream_t stream) {
    const float* x     = (const float*)d_in[0];
    const int*   ei    = (const int*)d_in[1];
    const float* W_in  = (const float*)d_in[2];
    const float* b_in  = (const float*)d_in[3];
    const float* W_t1  = (const float*)d_in[4];
    const float* b_t1  = (const float*)d_in[5];
    const float* W_t2  = (const float*)d_in[6];
    const float* b_t2  = (const float*)d_in[7];
    const float* W_ih  = (const float*)d_in[8];
    const float* b_ih  = (const float*)d_in[9];
    const float* W_hh  = (const float*)d_in[10];
    const float* b_hh  = (const float*)d_in[11];
    const float* W_out = (const float*)d_in[12];
    const float* b_out = (const float*)d_in[13];
    float* out = (float*)d_out;

    const int n = in_sizes[0] / IN_DIM;  // 100000
    const int e = in_sizes[1] / 2;       // 1000000
    const int* row = ei;
    const int* col = ei + e;

    char* ws = (char*)d_ws;
    float* X1  = (float*)ws;  ws += (size_t)n * KDIM * sizeof(float);   // 51.2 MB
    float* W2p = (float*)ws;  ws += (size_t)JOUT * KDIM * sizeof(float);
    float* B2  = (float*)ws;  ws += JOUT * sizeof(float);
    float* tau = (float*)ws;  ws += (size_t)n * sizeof(float);
    int* deg       = (int*)ws;  ws += (size_t)n * sizeof(int);
    int* row_start = (int*)ws;  ws += (size_t)n * sizeof(int);
    int* cursor    = (int*)ws;  ws += (size_t)n * sizeof(int);
    int* blk       = (int*)ws;  ws += SCAN_B * sizeof(int);
    int* cols      = (int*)ws;  ws += (size_t)e * sizeof(int);

    const int nb = (n + SCAN_B - 1) / SCAN_B;
    const int ntile = (n + 255) / 256;
    const int ngemm = (n + NT - 1) / NT;

    zero_int_kernel<<<(n + 255) / 256, 256, 0, stream>>>(deg, n);
    count_deg_kernel<<<(e + 255) / 256, 256, 0, stream>>>(row, deg, e, n);
    block_sum_kernel<<<nb, SCAN_B, 0, stream>>>(deg, blk, n);
    scan_blk_kernel<<<1, SCAN_B, 0, stream>>>(blk, nb);
    scan_final_kernel<<<nb, SCAN_B, 0, stream>>>(deg, blk, row_start, cursor, n);
    fill_csr_kernel<<<(e + 255) / 256, 256, 0, stream>>>(row, col, cursor, cols, e, n);

    prep_w2_kernel<<<1, 256, 0, stream>>>(W_ih, W_hh, b_ih, b_hh, W2p, B2);
    init_kernel<<<ntile, 256, 0, stream>>>(x, W_in, b_in, W_t1, b_t1,
                                           W_t2, b_t2, X1, tau, n);

    int hoff = 64, aoff = 0;  // h starts in cols [64,128)
    for (int it = 0; it < 5; ++it) {
        aggregate_kernel<<<((n * 16) + 255) / 256, 256, 0, stream>>>(
            X1, tau, row_start, deg, cols, n, hoff, aoff);
        gru_gemm_kernel<<<ngemm, 256, 0, stream>>>(X1, W2p, B2, n, hoff, aoff);
        int tmp = hoff; hoff = aoff; aoff = tmp;  // h' now lives where agg was
    }
    out_kernel<<<ntile, 256, 0, stream>>>(X1, W_out, b_out, out, n, hoff);
}

// Round 8
// 1401.259 us; speedup vs baseline: 14.1185x; 1.0710x over previous
//
#include <hip/hip_runtime.h>

#define HID 64
#define IN_DIM 128
#define TAU_DIM 8
#define SCAN_B 1024

#define KDIM 128        // X row = [agg(64) | h(64)]
#define NT 64           // nodes per GEMM block
#define JOUT 256        // padded gate outputs: [rz(128) | i_n(64) | h_n(64)]
#define XS_STRIDE 132   // 128 + 4 pad (f32 words)
#define WS_STRIDE 20    // 16 + 4 pad (f32 words)

// ---------------- CSR build (bounds-guarded) ----------------

__global__ void zero_int_kernel(int* __restrict__ p, int n) {
    int i = blockIdx.x * blockDim.x + threadIdx.x;
    if (i < n) p[i] = 0;
}

__global__ void count_deg_kernel(const int* __restrict__ row, int* __restrict__ deg,
                                 int e, int n) {
    int i = blockIdx.x * blockDim.x + threadIdx.x;
    if (i < e) {
        int r = row[i];
        if ((unsigned)r < (unsigned)n) atomicAdd(&deg[r], 1);
    }
}

__global__ void block_sum_kernel(const int* __restrict__ deg, int* __restrict__ blk, int n) {
    __shared__ int s[SCAN_B];
    int i = blockIdx.x * SCAN_B + threadIdx.x;
    s[threadIdx.x] = (i < n) ? deg[i] : 0;
    __syncthreads();
    for (int off = SCAN_B / 2; off > 0; off >>= 1) {
        if (threadIdx.x < off) s[threadIdx.x] += s[threadIdx.x + off];
        __syncthreads();
    }
    if (threadIdx.x == 0) blk[blockIdx.x] = s[0];
}

__global__ void scan_blk_kernel(int* __restrict__ blk, int nb) {
    __shared__ int s[SCAN_B];
    int v = (threadIdx.x < nb) ? blk[threadIdx.x] : 0;
    s[threadIdx.x] = v;
    __syncthreads();
    for (int off = 1; off < SCAN_B; off <<= 1) {
        int t = (threadIdx.x >= off) ? s[threadIdx.x - off] : 0;
        __syncthreads();
        s[threadIdx.x] += t;
        __syncthreads();
    }
    if (threadIdx.x < nb) blk[threadIdx.x] = s[threadIdx.x] - v;  // exclusive
}

__global__ void scan_final_kernel(const int* __restrict__ deg, const int* __restrict__ blk,
                                  int* __restrict__ row_start, int* __restrict__ cursor, int n) {
    __shared__ int s[SCAN_B];
    int i = blockIdx.x * SCAN_B + threadIdx.x;
    int v = (i < n) ? deg[i] : 0;
    s[threadIdx.x] = v;
    __syncthreads();
    for (int off = 1; off < SCAN_B; off <<= 1) {
        int t = (threadIdx.x >= off) ? s[threadIdx.x - off] : 0;
        __syncthreads();
        s[threadIdx.x] += t;
        __syncthreads();
    }
    if (i < n) {
        int excl = s[threadIdx.x] - v + blk[blockIdx.x];
        row_start[i] = excl;
        cursor[i]    = excl;
    }
}

__global__ void fill_csr_kernel(const int* __restrict__ row, const int* __restrict__ col,
                                int* __restrict__ cursor, int* __restrict__ cols,
                                int e, int n) {
    int i = blockIdx.x * blockDim.x + threadIdx.x;
    if (i < e) {
        int r = row[i];
        if ((unsigned)r < (unsigned)n) {
            int c = col[i];
            if ((unsigned)c >= (unsigned)n) c = 0;
            int p = atomicAdd(&cursor[r], 1);
            cols[p] = c;
        }
    }
}

// ---------------- weight repacks ----------------
// W2p [8][256][16]: GRU gates (rows 0..127 [Wih|Whh] r,z; 128..191 [Wih_n|0];
//                   192..255 [0|Whh_n]); B2[256].
// W1p [8][128][16]: init (rows 0..63 W_in, 64..127 W_t1; k = x dim); B1[128].
// Wop [4][64][16]:  out projection (k = h dim).

__global__ void prep_all_kernel(
    const float* __restrict__ W_ih, const float* __restrict__ W_hh,
    const float* __restrict__ b_ih, const float* __restrict__ b_hh,
    const float* __restrict__ W_in, const float* __restrict__ b_in,
    const float* __restrict__ W_t1, const float* __restrict__ b_t1,
    const float* __restrict__ W_out,
    float* __restrict__ W2p, float* __restrict__ B2,
    float* __restrict__ W1p, float* __restrict__ B1,
    float* __restrict__ Wop) {
    int j = threadIdx.x;  // 256 threads, 1 block
    {
        float b;
        if (j < 128)      b = b_ih[j] + b_hh[j];
        else if (j < 192) b = b_ih[j];
        else              b = b_hh[j - 64];
        B2[j] = b;
        for (int k = 0; k < KDIM; k++) {
            float v;
            if (j < 128)      v = (k < 64) ? W_ih[j * 64 + k] : W_hh[j * 64 + (k - 64)];
            else if (j < 192) v = (k < 64) ? W_ih[j * 64 + k] : 0.f;
            else              v = (k >= 64) ? W_hh[(j - 64) * 64 + (k - 64)] : 0.f;
            W2p[(size_t)(k >> 4) * (JOUT * 16) + j * 16 + (k & 15)] = v;
        }
    }
    if (j < 128) {
        B1[j] = (j < 64) ? b_in[j] : b_t1[j - 64];
        const float* src = (j < 64) ? (W_in + (size_t)j * IN_DIM)
                                    : (W_t1 + (size_t)(j - 64) * IN_DIM);
        for (int k = 0; k < IN_DIM; k++)
            W1p[(size_t)(k >> 4) * (128 * 16) + j * 16 + (k & 15)] = src[k];
    }
    if (j < 64) {
        for (int k = 0; k < HID; k++)
            Wop[(size_t)(k >> 4) * (64 * 16) + j * 16 + (k & 15)] = W_out[(size_t)j * HID + k];
    }
}

// ---------------- init as tiled GEMM: h0 + tau ----------------
// Block: 64 nodes x 128 outs (j<64: h0 = relu(x@W_in.T+b); j>=64: t1 =
// relu(x@W_t1.T+b)), K=128. Thread (tx,ty) owns 4 nodes x 8 outs (2 quads).
// t1 tile -> LDS, then 64 threads finish tau = mean(sigmoid(t1@W_t2.T+b_t2)).

__global__ __launch_bounds__(256) void init_gemm_kernel(
    const float* __restrict__ x, const float* __restrict__ W1p,
    const float* __restrict__ B1,
    const float* __restrict__ W_t2, const float* __restrict__ b_t2,
    float* __restrict__ X1, float* __restrict__ tau, int n) {
    __shared__ float xs[NT * XS_STRIDE];     // 33 KB
    __shared__ float wsh[128 * WS_STRIDE];   // 10 KB
    __shared__ float t1s[NT][HID + 1];       // 16.6 KB

    const int t  = threadIdx.x;
    const int tx = t & 15;
    const int ty = t >> 4;
    const int node0 = blockIdx.x * NT;

    // stage x tile: 64 rows x 32 float4
#pragma unroll
    for (int i = 0; i < 8; i++) {
        int f4 = i * 256 + t;
        int r  = f4 >> 5;
        int c4 = f4 & 31;
        float4 v = make_float4(0.f, 0.f, 0.f, 0.f);
        int node = node0 + r;
        if (node < n) v = *(const float4*)(x + (size_t)node * IN_DIM + c4 * 4);
        *(float4*)(xs + r * XS_STRIDE + c4 * 4) = v;
    }

    float acc[4][2][4];  // [nd][gb][i]; j = gb*64 + i*16 + tx
#pragma unroll
    for (int gb = 0; gb < 2; gb++)
#pragma unroll
        for (int i = 0; i < 4; i++) {
            float b = B1[gb * 64 + i * 16 + tx];
#pragma unroll
            for (int nd = 0; nd < 4; nd++) acc[nd][gb][i] = b;
        }

#pragma unroll 1
    for (int kc = 0; kc < 8; kc++) {
        __syncthreads();
        {
            const float4* src = (const float4*)(W1p + (size_t)kc * (128 * 16));
#pragma unroll
            for (int i = 0; i < 2; i++) {
                int f4  = i * 256 + t;  // 0..511
                int row = f4 >> 2;
                int k4  = f4 & 3;
                *(float4*)(wsh + row * WS_STRIDE + k4 * 4) = src[f4];
            }
        }
        __syncthreads();
#pragma unroll 1
        for (int k4 = 0; k4 < 4; k4++) {
            float4 xv[4];
#pragma unroll
            for (int nd = 0; nd < 4; nd++)
                xv[nd] = *(const float4*)(xs + (ty * 4 + nd) * XS_STRIDE + kc * 16 + k4 * 4);
#pragma unroll
            for (int gb = 0; gb < 2; gb++)
#pragma unroll
                for (int i = 0; i < 4; i++) {
                    float4 w = *(const float4*)(wsh + (gb * 64 + i * 16 + tx) * WS_STRIDE + k4 * 4);
#pragma unroll
                    for (int nd = 0; nd < 4; nd++) {
                        acc[nd][gb][i] += w.x * xv[nd].x + w.y * xv[nd].y
                                        + w.z * xv[nd].z + w.w * xv[nd].w;
                    }
                }
        }
    }

    // epilogue: h0 -> X1 cols [64,128); t1 -> LDS
#pragma unroll
    for (int nd = 0; nd < 4; nd++) {
        int r = ty * 4 + nd;
        int node = node0 + r;
#pragma unroll
        for (int i = 0; i < 4; i++) {
            float h0 = fmaxf(acc[nd][0][i], 0.f);
            float t1 = fmaxf(acc[nd][1][i], 0.f);
            if (node < n) X1[(size_t)node * KDIM + 64 + i * 16 + tx] = h0;
            t1s[r][i * 16 + tx] = t1;
        }
    }
    __syncthreads();

    if (t < NT) {
        int node = node0 + t;
        if (node < n) {
            float tsum = 0.f;
#pragma unroll 1
            for (int m = 0; m < TAU_DIM; m++) {
                float a = b_t2[m];
                const float* wr = W_t2 + (size_t)m * HID;
#pragma unroll
                for (int k = 0; k < HID; k++) a += wr[k] * t1s[t][k];
                tsum += 1.f / (1.f + expf(-a));
            }
            tau[node] = tsum * (1.f / TAU_DIM);
        }
    }
}

// ---------------- aggregate: X1[v][aoff..] = tau[v] * sum |h[v]-h[col]| ----------------

__global__ __launch_bounds__(256) void aggregate_kernel(
    float* __restrict__ X1, const float* __restrict__ tau,
    const int* __restrict__ row_start, const int* __restrict__ deg,
    const int* __restrict__ cols, int n, int hoff, int aoff) {
    int t = blockIdx.x * blockDim.x + threadIdx.x;
    int v = t >> 4;
    if (v >= n) return;
    int c4 = (t & 15) * 4;

    float4 hv = *(const float4*)(X1 + (size_t)v * KDIM + hoff + c4);
    float4 s0 = make_float4(0.f, 0.f, 0.f, 0.f);
    float4 s1 = make_float4(0.f, 0.f, 0.f, 0.f);
    int st = row_start[v];
    int d  = deg[v];
    int i = 0;
    for (; i + 1 < d; i += 2) {
        int c0 = cols[st + i];
        int c1 = cols[st + i + 1];
        float4 hc0 = *(const float4*)(X1 + (size_t)c0 * KDIM + hoff + c4);
        float4 hc1 = *(const float4*)(X1 + (size_t)c1 * KDIM + hoff + c4);
        s0.x += fabsf(hv.x - hc0.x);
        s0.y += fabsf(hv.y - hc0.y);
        s0.z += fabsf(hv.z - hc0.z);
        s0.w += fabsf(hv.w - hc0.w);
        s1.x += fabsf(hv.x - hc1.x);
        s1.y += fabsf(hv.y - hc1.y);
        s1.z += fabsf(hv.z - hc1.z);
        s1.w += fabsf(hv.w - hc1.w);
    }
    if (i < d) {
        int c = cols[st + i];
        float4 hc = *(const float4*)(X1 + (size_t)c * KDIM + hoff + c4);
        s0.x += fabsf(hv.x - hc.x);
        s0.y += fabsf(hv.y - hc.y);
        s0.z += fabsf(hv.z - hc.z);
        s0.w += fabsf(hv.w - hc.w);
    }
    float tv = tau[v];
    *(float4*)(X1 + (size_t)v * KDIM + aoff + c4) =
        make_float4((s0.x + s1.x) * tv, (s0.y + s1.y) * tv,
                    (s0.z + s1.z) * tv, (s0.w + s1.w) * tv);
}

// ---------------- GRU as tiled GEMM + fused gating (round-7 verified) ----------------

__global__ __launch_bounds__(256) void gru_gemm_kernel(
    float* __restrict__ X1, const float* __restrict__ W2p,
    const float* __restrict__ B2, int n, int hoff, int aoff) {
    __shared__ float xs[NT * XS_STRIDE];    // 33 KB
    __shared__ float wsh[JOUT * WS_STRIDE]; // 20 KB

    const int t  = threadIdx.x;
    const int tx = t & 15;
    const int ty = t >> 4;
    const int node0 = blockIdx.x * NT;

    {
        const int aoff4 = aoff >> 2, hoff4 = hoff >> 2;
#pragma unroll
        for (int i = 0; i < 8; i++) {
            int f4 = i * 256 + t;
            int r  = f4 >> 5;
            int c4 = f4 & 31;
            int src4 = (c4 < 16) ? (aoff4 + c4) : (hoff4 + (c4 - 16));
            float4 v = make_float4(0.f, 0.f, 0.f, 0.f);
            int node = node0 + r;
            if (node < n) v = *(const float4*)(X1 + (size_t)node * KDIM + src4 * 4);
            *(float4*)(xs + r * XS_STRIDE + c4 * 4) = v;
        }
    }

    float acc[4][4][4];  // [nd][gate-quad][i]; j = gb*64 + i*16 + tx
#pragma unroll
    for (int gb = 0; gb < 4; gb++)
#pragma unroll
        for (int i = 0; i < 4; i++) {
            float b = B2[gb * 64 + i * 16 + tx];
#pragma unroll
            for (int nd = 0; nd < 4; nd++) acc[nd][gb][i] = b;
        }

#pragma unroll 1
    for (int kc = 0; kc < 8; kc++) {
        __syncthreads();
        {
            const float4* src = (const float4*)(W2p + (size_t)kc * (JOUT * 16));
#pragma unroll
            for (int i = 0; i < 4; i++) {
                int f4  = i * 256 + t;
                int row = f4 >> 2;
                int k4  = f4 & 3;
                *(float4*)(wsh + row * WS_STRIDE + k4 * 4) = src[f4];
            }
        }
        __syncthreads();
#pragma unroll 1
        for (int k4 = 0; k4 < 4; k4++) {
            float4 xv[4];
#pragma unroll
            for (int nd = 0; nd < 4; nd++)
                xv[nd] = *(const float4*)(xs + (ty * 4 + nd) * XS_STRIDE + kc * 16 + k4 * 4);
#pragma unroll
            for (int gb = 0; gb < 4; gb++)
#pragma unroll
                for (int i = 0; i < 4; i++) {
                    float4 w = *(const float4*)(wsh + (gb * 64 + i * 16 + tx) * WS_STRIDE + k4 * 4);
#pragma unroll
                    for (int nd = 0; nd < 4; nd++) {
                        acc[nd][gb][i] += w.x * xv[nd].x + w.y * xv[nd].y
                                        + w.z * xv[nd].z + w.w * xv[nd].w;
                    }
                }
        }
    }

#pragma unroll
    for (int nd = 0; nd < 4; nd++) {
        int node = node0 + ty * 4 + nd;
        if (node < n) {
#pragma unroll
            for (int i = 0; i < 4; i++) {
                float r  = 1.f / (1.f + expf(-acc[nd][0][i]));
                float z  = 1.f / (1.f + expf(-acc[nd][1][i]));
                float nn = tanhf(acc[nd][2][i] + r * acc[nd][3][i]);
                float hold = xs[(ty * 4 + nd) * XS_STRIDE + 64 + i * 16 + tx];
                X1[(size_t)node * KDIM + aoff + i * 16 + tx] = (1.f - z) * nn + z * hold;
            }
        }
    }
}

// ---------------- output projection as tiled GEMM ----------------
// Block: 64 nodes x 64 outs, K=64 (h). Thread owns 4 nodes x 4 outs.

__global__ __launch_bounds__(256) void out_gemm_kernel(
    const float* __restrict__ X1, const float* __restrict__ Wop,
    const float* __restrict__ b_out, float* __restrict__ out, int n, int hoff) {
    __shared__ float xs[NT * 68];          // 17.4 KB (64 + 4 pad)
    __shared__ float wsh[64 * WS_STRIDE];  // 5 KB

    const int t  = threadIdx.x;
    const int tx = t & 15;
    const int ty = t >> 4;
    const int node0 = blockIdx.x * NT;

    // stage h tile: 64 rows x 16 float4
#pragma unroll
    for (int i = 0; i < 4; i++) {
        int f4 = i * 256 + t;
        int r  = f4 >> 4;
        int c4 = f4 & 15;
        float4 v = make_float4(0.f, 0.f, 0.f, 0.f);
        int node = node0 + r;
        if (node < n) v = *(const float4*)(X1 + (size_t)node * KDIM + hoff + c4 * 4);
        *(float4*)(xs + r * 68 + c4 * 4) = v;
    }

    float acc[4][4];  // [nd][i]; j = i*16 + tx
#pragma unroll
    for (int i = 0; i < 4; i++) {
        float b = b_out[i * 16 + tx];
#pragma unroll
        for (int nd = 0; nd < 4; nd++) acc[nd][i] = b;
    }

#pragma unroll 1
    for (int kc = 0; kc < 4; kc++) {
        __syncthreads();
        {
            const float4* src = (const float4*)(Wop + (size_t)kc * (64 * 16));
            int f4  = t;  // 0..255
            int row = f4 >> 2;
            int k4  = f4 & 3;
            *(float4*)(wsh + row * WS_STRIDE + k4 * 4) = src[f4];
        }
        __syncthreads();
#pragma unroll 1
        for (int k4 = 0; k4 < 4; k4++) {
            float4 xv[4];
#pragma unroll
            for (int nd = 0; nd < 4; nd++)
                xv[nd] = *(const float4*)(xs + (ty * 4 + nd) * 68 + kc * 16 + k4 * 4);
#pragma unroll
            for (int i = 0; i < 4; i++) {
                float4 w = *(const float4*)(wsh + (i * 16 + tx) * WS_STRIDE + k4 * 4);
#pragma unroll
                for (int nd = 0; nd < 4; nd++) {
                    acc[nd][i] += w.x * xv[nd].x + w.y * xv[nd].y
                                + w.z * xv[nd].z + w.w * xv[nd].w;
                }
            }
        }
    }

#pragma unroll
    for (int nd = 0; nd < 4; nd++) {
        int node = node0 + ty * 4 + nd;
        if (node < n) {
#pragma unroll
            for (int i = 0; i < 4; i++)
                out[(size_t)node * HID + i * 16 + tx] = acc[nd][i];
        }
    }
}

// ---------------- launch ----------------

extern "C" void kernel_launch(void* const* d_in, const int* in_sizes, int n_in,
                              void* d_out, int out_size, void* d_ws, size_t ws_size,
                              hipStream_t stream) {
    const float* x     = (const float*)d_in[0];
    const int*   ei    = (const int*)d_in[1];
    const float* W_in  = (const float*)d_in[2];
    const float* b_in  = (const float*)d_in[3];
    const float* W_t1  = (const float*)d_in[4];
    const float* b_t1  = (const float*)d_in[5];
    const float* W_t2  = (const float*)d_in[6];
    const float* b_t2  = (const float*)d_in[7];
    const float* W_ih  = (const float*)d_in[8];
    const float* b_ih  = (const float*)d_in[9];
    const float* W_hh  = (const float*)d_in[10];
    const float* b_hh  = (const float*)d_in[11];
    const float* W_out = (const float*)d_in[12];
    const float* b_out = (const float*)d_in[13];
    float* out = (float*)d_out;

    const int n = in_sizes[0] / IN_DIM;  // 100000
    const int e = in_sizes[1] / 2;       // 1000000
    const int* row = ei;
    const int* col = ei + e;

    char* ws = (char*)d_ws;
    float* X1  = (float*)ws;  ws += (size_t)n * KDIM * sizeof(float);   // 51.2 MB
    float* W2p = (float*)ws;  ws += (size_t)JOUT * KDIM * sizeof(float);
    float* B2  = (float*)ws;  ws += JOUT * sizeof(float);
    float* W1p = (float*)ws;  ws += (size_t)128 * IN_DIM * sizeof(float);
    float* B1  = (float*)ws;  ws += 128 * sizeof(float);
    float* Wop = (float*)ws;  ws += (size_t)64 * HID * sizeof(float);
    float* tau = (float*)ws;  ws += (size_t)n * sizeof(float);
    int* deg       = (int*)ws;  ws += (size_t)n * sizeof(int);
    int* row_start = (int*)ws;  ws += (size_t)n * sizeof(int);
    int* cursor    = (int*)ws;  ws += (size_t)n * sizeof(int);
    int* blk       = (int*)ws;  ws += SCAN_B * sizeof(int);
    int* cols      = (int*)ws;  ws += (size_t)e * sizeof(int);

    const int nb = (n + SCAN_B - 1) / SCAN_B;
    const int ngemm = (n + NT - 1) / NT;

    zero_int_kernel<<<(n + 255) / 256, 256, 0, stream>>>(deg, n);
    count_deg_kernel<<<(e + 255) / 256, 256, 0, stream>>>(row, deg, e, n);
    block_sum_kernel<<<nb, SCAN_B, 0, stream>>>(deg, blk, n);
    scan_blk_kernel<<<1, SCAN_B, 0, stream>>>(blk, nb);
    scan_final_kernel<<<nb, SCAN_B, 0, stream>>>(deg, blk, row_start, cursor, n);
    fill_csr_kernel<<<(e + 255) / 256, 256, 0, stream>>>(row, col, cursor, cols, e, n);

    prep_all_kernel<<<1, 256, 0, stream>>>(W_ih, W_hh, b_ih, b_hh,
                                           W_in, b_in, W_t1, b_t1, W_out,
                                           W2p, B2, W1p, B1, Wop);
    init_gemm_kernel<<<ngemm, 256, 0, stream>>>(x, W1p, B1, W_t2, b_t2, X1, tau, n);

    int hoff = 64, aoff = 0;  // h starts in cols [64,128)
    for (int it = 0; it < 5; ++it) {
        aggregate_kernel<<<((n * 16) + 255) / 256, 256, 0, stream>>>(
            X1, tau, row_start, deg, cols, n, hoff, aoff);
        gru_gemm_kernel<<<ngemm, 256, 0, stream>>>(X1, W2p, B2, n, hoff, aoff);
        int tmp = hoff; hoff = aoff; aoff = tmp;  // h' now lives where agg was
    }
    out_gemm_kernel<<<ngemm, 256, 0, stream>>>(X1, Wop, b_out, out, n, hoff);
}